// Round 3
// baseline (219.801 us; speedup 1.0000x reference)
//
#include <hip/hip_runtime.h>
#include <stdint.h>

#define EPS 1e-5f

typedef float f32x4 __attribute__((ext_vector_type(4)));
typedef __bf16 bf16x8 __attribute__((ext_vector_type(8)));

__device__ __forceinline__ ushort f2bf(float f){
  union { float f; uint32_t u; } v; v.f = f;
  uint32_t r = v.u + 0x7fffu + ((v.u >> 16) & 1u);
  return (ushort)(r >> 16);
}

__device__ __forceinline__ float bf2f(ushort u){
  union { uint32_t u; float f; } v; v.u = ((uint32_t)u) << 16;
  return v.f;
}

__device__ __forceinline__ uint32_t pk2bf(float a, float b){
  __bf16 x = (__bf16)a, y = (__bf16)b;
  return (uint32_t)__builtin_bit_cast(ushort, x) |
         ((uint32_t)__builtin_bit_cast(ushort, y) << 16);
}

__device__ __forceinline__ f32x4 mfma16(bf16x8 a, bf16x8 b, f32x4 c){
  return __builtin_amdgcn_mfma_f32_16x16x32_bf16(a, b, c, 0, 0, 0);
}

// ---------------- prep: weights f32 -> bf16 ----------------
__global__ __launch_bounds__(256) void k_prep(const float* wq, const float* wp,
                                              ushort* wqb, ushort* wpb){
  int i = blockIdx.x * 256 + threadIdx.x;
  if (i < 3*256*256) wqb[i] = f2bf(wq[i]);
  if (i < 256*256)   wpb[i] = f2bf(wp[i]);
}

// ---------------- groupnorm stats stage 1 ----------------
// grid: 16 (b,g) * 64 partial blocks; each block sums 2048 floats
__global__ __launch_bounds__(256) void k_gn1(const float* x, float2* part){
  int bg = blockIdx.x >> 6, pb = blockIdx.x & 63;
  const f32x4* base = (const f32x4*)(x + (size_t)bg*131072 + (size_t)pb*2048);
  float s = 0.f, ss = 0.f;
  #pragma unroll
  for (int it = 0; it < 2; ++it){
    f32x4 v = base[threadIdx.x + it*256];
    #pragma unroll
    for (int j = 0; j < 4; ++j){ s += v[j]; ss += v[j]*v[j]; }
  }
  #pragma unroll
  for (int off = 1; off < 64; off <<= 1){
    s  += __shfl_xor(s,  off);
    ss += __shfl_xor(ss, off);
  }
  __shared__ float red[8];
  int wid = threadIdx.x >> 6;
  if ((threadIdx.x & 63) == 0){ red[wid] = s; red[4 + wid] = ss; }
  __syncthreads();
  if (threadIdx.x == 0){
    part[blockIdx.x] = make_float2(red[0]+red[1]+red[2]+red[3],
                                   red[4]+red[5]+red[6]+red[7]);
  }
}

// ---------------- normalize + transpose: x -> Xn[b][n][c] bf16 ----------------
// folds gn stage-2; grid (64 nt, 4 ctile, 2 b) x 256
__global__ __launch_bounds__(256) void k_norm(const float* x, const float* gamma, const float* beta,
                                              const float2* part, ushort* Xn){
  __shared__ float T[64][65];     // [n_local][c_local]
  __shared__ float2 st[2];
  int nt = blockIdx.x, ct = blockIdx.y, b = blockIdx.z;
  int t = threadIdx.x, wid = t >> 6, ln = t & 63;

  if (wid < 2){
    float2 p = part[((b*8) + ct*2 + wid)*64 + ln];
    float s = p.x, ss = p.y;
    #pragma unroll
    for (int off = 1; off < 64; off <<= 1){
      s  += __shfl_xor(s,  off);
      ss += __shfl_xor(ss, off);
    }
    if (ln == 0){
      const float inv = 1.f / 131072.f;
      float mean = s * inv;
      float var  = ss * inv - mean*mean;
      st[wid] = make_float2(mean, rsqrtf(var + EPS));
    }
  }
  __syncthreads();

  int c_local = t >> 2, col0 = (t & 3) * 16;
  float2 s0 = st[c_local >> 5];
  float g  = gamma[ct*64 + c_local] * s0.y;
  float bt = beta[ct*64 + c_local] - s0.x * g;
  const float* xr = x + ((size_t)(b*256 + ct*64 + c_local))*4096 + nt*64 + col0;
  #pragma unroll
  for (int j = 0; j < 4; ++j){
    f32x4 v = *(const f32x4*)(xr + j*4);
    #pragma unroll
    for (int e = 0; e < 4; ++e) T[col0 + j*4 + e][c_local] = v[e]*g + bt;
  }
  __syncthreads();

  int n_local = t >> 2, c0 = (t & 3) * 16;
  uint32_t pk[8];
  #pragma unroll
  for (int j = 0; j < 8; ++j) pk[j] = pk2bf(T[n_local][c0 + 2*j], T[n_local][c0 + 2*j + 1]);
  ushort* dst = Xn + ((size_t)b*4096 + nt*64 + n_local)*256 + ct*64 + c0;
  *(uint4*)dst       = make_uint4(pk[0], pk[1], pk[2], pk[3]);
  *(uint4*)(dst + 8) = make_uint4(pk[4], pk[5], pk[6], pk[7]);
}

// ---------------- QKV GEMM (pure MFMA, A from Xn) ----------------
// out^T[n][o] = Xn[n][c] * W[o][c];  grid (64 nt, 12 ot, 2 b) x 256
__global__ __launch_bounds__(256) void k_qkv(const ushort* Xn, const ushort* wqb, const float* bqkv,
                                             ushort* Qb, ushort* Kb, ushort* Vb){
  __shared__ ushort T[64][72];
  int nt = blockIdx.x, ot = blockIdx.y, b = blockIdx.z;
  int t = threadIdx.x, lane = t & 63, wid = t >> 6, l15 = lane & 15, g4 = lane >> 4;
  int o = ot*64 + wid*16 + l15;
  const ushort* A = Xn + ((size_t)b*4096 + nt*64)*256;

  f32x4 acc[4];
  #pragma unroll
  for (int m = 0; m < 4; ++m) acc[m] = (f32x4){0.f,0.f,0.f,0.f};

  #pragma unroll
  for (int ks = 0; ks < 8; ++ks){
    bf16x8 bw = *(const bf16x8*)(wqb + (size_t)o*256 + ks*32 + g4*8);
    #pragma unroll
    for (int mf = 0; mf < 4; ++mf){
      bf16x8 aa = *(const bf16x8*)(A + (size_t)(mf*16 + l15)*256 + ks*32 + g4*8);
      acc[mf] = mfma16(aa, bw, acc[mf]);
    }
  }

  int tt = ot >> 2, h = ot & 3;
  int bh = b*4 + h;
  float bias = bqkv[o];
  if (tt == 2){
    int d = wid*16 + l15;
    ushort* dst = Vb + ((size_t)bh*64 + d)*4096;
    #pragma unroll
    for (int mf = 0; mf < 4; ++mf){
      int n0 = nt*64 + mf*16 + g4*4;
      uint32_t w0 = pk2bf(acc[mf][0]+bias, acc[mf][1]+bias);
      uint32_t w1 = pk2bf(acc[mf][2]+bias, acc[mf][3]+bias);
      *(uint2*)(dst + n0) = make_uint2(w0, w1);
    }
  } else {
    int d = wid*16 + l15;
    #pragma unroll
    for (int mf = 0; mf < 4; ++mf)
      #pragma unroll
      for (int r = 0; r < 4; ++r)
        T[mf*16 + g4*4 + r][d] = f2bf(acc[mf][r] + bias);
    __syncthreads();
    int n_local = t >> 2, d0 = (t & 3) * 16;
    ushort* dst = (tt == 0 ? Qb : Kb) + ((size_t)bh*4096 + nt*64 + n_local)*64 + d0;
    *(uint4*)dst       = *(uint4*)&T[n_local][d0];
    *(uint4*)(dst + 8) = *(uint4*)&T[n_local][d0 + 8];
  }
}

// ---------------- flash attention, split-KV, XCD-swizzled ----------------
// grid: 512*SPLIT flat; XCD x owns bh=x. 4 waves x 16 q-rows.
template<int SPLIT>
__global__ __launch_bounds__(256) void k_attn(const ushort* Qb, const ushort* Kb,
                                              const ushort* Vb, ushort* Opart, float2* ML){
  __shared__ ushort Kl[2][64][72];
  __shared__ ushort Vl[2][64][72];
  __shared__ ushort Pl[4][16][72];
  const float SCL2 = 0.125f * 1.44269504f;   // scale * log2(e)

  int nwg = 512*SPLIT;
  int w = (blockIdx.x & 7) * (nwg >> 3) + (blockIdx.x >> 3);
  int per_bh = 64*SPLIT;
  int bh = w / per_bh, rem = w % per_bh;
  int qt = rem & 63, half = rem >> 6;
  int b = bh >> 2;

  int t = threadIdx.x, lane = t & 63, wid = t >> 6, l15 = lane & 15, g4 = lane >> 4;

  const ushort* Qg = Qb + ((size_t)bh*4096 + qt*64 + wid*16 + l15)*64 + g4*8;
  bf16x8 aq0 = *(const bf16x8*)Qg;
  bf16x8 aq1 = *(const bf16x8*)(Qg + 32);

  f32x4 oacc[4];
  #pragma unroll
  for (int m = 0; m < 4; ++m) oacc[m] = (f32x4){0.f,0.f,0.f,0.f};
  float m_s = -INFINITY, l_s = 0.f;   // per lane, q = l15 (replicated over g4)

  const ushort* Kgb = Kb + (size_t)bh*4096*64;
  const ushort* Vgb = Vb + (size_t)bh*64*4096;

  const int iters = 64 / SPLIT;
  const int kb0 = half * iters, kbEnd = kb0 + iters;

  int r0 = t >> 3, seg = (t & 7)*8;
  // stage first tile
  {
    const ushort* Kg = Kgb + (size_t)kb0*64*64;
    *(uint4*)&Kl[0][r0][seg]    = *(const uint4*)(Kg + (size_t)r0*64 + seg);
    *(uint4*)&Kl[0][r0+32][seg] = *(const uint4*)(Kg + (size_t)(r0+32)*64 + seg);
    *(uint4*)&Vl[0][r0][seg]    = *(const uint4*)(Vgb + (size_t)r0*4096 + kb0*64 + seg);
    *(uint4*)&Vl[0][r0+32][seg] = *(const uint4*)(Vgb + (size_t)(r0+32)*4096 + kb0*64 + seg);
  }
  __syncthreads();

  for (int kb = kb0; kb < kbEnd; ++kb){
    int cur = kb & 1;
    uint4 kr0, kr1, vr0, vr1;
    if (kb < kbEnd - 1){
      const ushort* Kg = Kgb + (size_t)(kb+1)*64*64;
      kr0 = *(const uint4*)(Kg + (size_t)r0*64 + seg);
      kr1 = *(const uint4*)(Kg + (size_t)(r0+32)*64 + seg);
      vr0 = *(const uint4*)(Vgb + (size_t)r0*4096 + (kb+1)*64 + seg);
      vr1 = *(const uint4*)(Vgb + (size_t)(r0+32)*4096 + (kb+1)*64 + seg);
    }

    // S^T = K · Q^T :  lane holds S[q=l15][k = ct*16 + g4*4 + r]
    f32x4 s[4];
    #pragma unroll
    for (int m = 0; m < 4; ++m) s[m] = (f32x4){0.f,0.f,0.f,0.f};
    __builtin_amdgcn_s_setprio(1);
    #pragma unroll
    for (int ks = 0; ks < 2; ++ks){
      bf16x8 bq = ks ? aq1 : aq0;
      #pragma unroll
      for (int ct = 0; ct < 4; ++ct){
        bf16x8 kf = *(const bf16x8*)&Kl[cur][ct*16 + l15][ks*32 + g4*8];
        s[ct] = mfma16(kf, bq, s[ct]);
      }
    }
    __builtin_amdgcn_s_setprio(0);

    // lane-local softmax (exp2 domain), defer-max THR=8
    float v01 = fmaxf(fmaxf(s[0][0], s[0][1]), fmaxf(s[0][2], s[0][3]));
    float v23 = fmaxf(fmaxf(s[1][0], s[1][1]), fmaxf(s[1][2], s[1][3]));
    float v45 = fmaxf(fmaxf(s[2][0], s[2][1]), fmaxf(s[2][2], s[2][3]));
    float v67 = fmaxf(fmaxf(s[3][0], s[3][1]), fmaxf(s[3][2], s[3][3]));
    float vmax = fmaxf(fmaxf(v01, v23), fmaxf(v45, v67));
    vmax = fmaxf(vmax, __shfl_xor(vmax, 16));
    vmax = fmaxf(vmax, __shfl_xor(vmax, 32));
    vmax *= SCL2;
    if (__any(vmax > m_s + 8.f)){
      float mn = fmaxf(m_s, vmax);
      float a = __builtin_amdgcn_exp2f(m_s - mn);
      m_s = mn;
      l_s *= a;
      float ar[4];
      #pragma unroll
      for (int r = 0; r < 4; ++r) ar[r] = __shfl(a, g4*4 + r);
      #pragma unroll
      for (int dt = 0; dt < 4; ++dt)
        #pragma unroll
        for (int r = 0; r < 4; ++r) oacc[dt][r] *= ar[r];
    }
    float rs = 0.f;
    float p[4][4];
    #pragma unroll
    for (int ct = 0; ct < 4; ++ct)
      #pragma unroll
      for (int r = 0; r < 4; ++r){
        float e = __builtin_amdgcn_exp2f(__builtin_fmaf(s[ct][r], SCL2, -m_s));
        p[ct][r] = e; rs += e;
      }
    rs += __shfl_xor(rs, 16);
    rs += __shfl_xor(rs, 32);
    l_s += rs;

    // P exchange through per-wave LDS (no barrier needed)
    #pragma unroll
    for (int ct = 0; ct < 4; ++ct){
      *(uint32_t*)&Pl[wid][l15][ct*16 + g4*4]     = pk2bf(p[ct][0], p[ct][1]);
      *(uint32_t*)&Pl[wid][l15][ct*16 + g4*4 + 2] = pk2bf(p[ct][2], p[ct][3]);
    }

    // PV
    __builtin_amdgcn_s_setprio(1);
    #pragma unroll
    for (int ks = 0; ks < 2; ++ks){
      bf16x8 pf = *(const bf16x8*)&Pl[wid][l15][ks*32 + g4*8];
      #pragma unroll
      for (int dt = 0; dt < 4; ++dt){
        bf16x8 vf = *(const bf16x8*)&Vl[cur][dt*16 + l15][ks*32 + g4*8];
        oacc[dt] = mfma16(pf, vf, oacc[dt]);
      }
    }
    __builtin_amdgcn_s_setprio(0);

    if (kb < kbEnd - 1){
      *(uint4*)&Kl[cur^1][r0][seg]    = kr0;
      *(uint4*)&Kl[cur^1][r0+32][seg] = kr1;
      *(uint4*)&Vl[cur^1][r0][seg]    = vr0;
      *(uint4*)&Vl[cur^1][r0+32][seg] = vr1;
      __syncthreads();
    }
  }

  // store raw partial O + (m,l)
  int pb = (bh*SPLIT + half)*64 + qt;
  if (g4 == 0) ML[(size_t)pb*64 + wid*16 + l15] = make_float2(m_s, l_s);
  ushort* dst = Opart + (size_t)pb*4096;
  #pragma unroll
  for (int r = 0; r < 4; ++r){
    int n_local = wid*16 + g4*4 + r;
    #pragma unroll
    for (int dt = 0; dt < 4; ++dt)
      dst[(size_t)n_local*64 + dt*16 + l15] = f2bf(oacc[dt][r]);
  }
}

// ---------------- combine split-KV partials -> AO[b][n][c] ----------------
// grid (64 qt, 8 bh) x 256
template<int SPLIT>
__global__ __launch_bounds__(256) void k_comb(const ushort* Opart, const float2* ML, ushort* AO){
  int qt = blockIdx.x, bh = blockIdx.y;
  int b = bh >> 2, h = bh & 3;
  int t = threadIdx.x, n_local = t >> 2, d0 = (t & 3) * 16;
  int pb1 = (bh*SPLIT)*64 + qt;
  float2 ml1 = ML[(size_t)pb1*64 + n_local];
  const ushort* o1 = Opart + (size_t)pb1*4096 + n_local*64 + d0;
  ushort* dst = AO + ((size_t)b*4096 + qt*64 + n_local)*256 + h*64 + d0;

  uint4 a0 = *(const uint4*)o1;
  uint4 a1 = *(const uint4*)(o1 + 8);
  const ushort* u1 = (const ushort*)&a0;   // [0..7], then a1
  uint32_t pk[8];
  if (SPLIT == 1){
    float inv = 1.f / ml1.y;
    float vals[16];
    #pragma unroll
    for (int j = 0; j < 8; ++j) vals[j]   = bf2f(((const ushort*)&a0)[j]) * inv;
    #pragma unroll
    for (int j = 0; j < 8; ++j) vals[j+8] = bf2f(((const ushort*)&a1)[j]) * inv;
    #pragma unroll
    for (int j = 0; j < 8; ++j) pk[j] = pk2bf(vals[2*j], vals[2*j+1]);
  } else {
    int pb2 = pb1 + 64;
    float2 ml2 = ML[(size_t)pb2*64 + n_local];
    const ushort* o2 = Opart + (size_t)pb2*4096 + n_local*64 + d0;
    uint4 b0 = *(const uint4*)o2;
    uint4 b1 = *(const uint4*)(o2 + 8);
    float m  = fmaxf(ml1.x, ml2.x);
    float e1 = __builtin_amdgcn_exp2f(ml1.x - m);
    float e2 = __builtin_amdgcn_exp2f(ml2.x - m);
    float inv = 1.f / (ml1.y*e1 + ml2.y*e2);
    float f1 = e1 * inv, f2 = e2 * inv;
    float vals[16];
    #pragma unroll
    for (int j = 0; j < 8; ++j)
      vals[j]   = bf2f(((const ushort*)&a0)[j])*f1 + bf2f(((const ushort*)&b0)[j])*f2;
    #pragma unroll
    for (int j = 0; j < 8; ++j)
      vals[j+8] = bf2f(((const ushort*)&a1)[j])*f1 + bf2f(((const ushort*)&b1)[j])*f2;
    #pragma unroll
    for (int j = 0; j < 8; ++j) pk[j] = pk2bf(vals[2*j], vals[2*j+1]);
  }
  (void)u1;
  *(uint4*)dst       = make_uint4(pk[0], pk[1], pk[2], pk[3]);
  *(uint4*)(dst + 8) = make_uint4(pk[4], pk[5], pk[6], pk[7]);
}

// ---------------- proj GEMM + bias + residual ----------------
__global__ __launch_bounds__(256) void k_proj(const ushort* AO, const ushort* wpb, const float* bproj,
                                              const float* x, float* out){
  int nt = blockIdx.x, ct = blockIdx.y, b = blockIdx.z;
  int t = threadIdx.x, lane = t & 63, wid = t >> 6, l15 = lane & 15, g4 = lane >> 4;
  int o = ct*64 + wid*16 + l15;
  f32x4 acc[4];
  #pragma unroll
  for (int m = 0; m < 4; ++m) acc[m] = (f32x4){0.f,0.f,0.f,0.f};

  #pragma unroll
  for (int ks = 0; ks < 8; ++ks){
    bf16x8 bw = *(const bf16x8*)(wpb + (size_t)o*256 + ks*32 + g4*8);
    #pragma unroll
    for (int mf = 0; mf < 4; ++mf){
      int n = nt*64 + mf*16 + l15;
      bf16x8 aa = *(const bf16x8*)(AO + ((size_t)b*4096 + n)*256 + ks*32 + g4*8);
      acc[mf] = mfma16(aa, bw, acc[mf]);
    }
  }

  float bias = bproj[o];
  size_t cbase = ((size_t)b*256 + o)*4096;
  #pragma unroll
  for (int mf = 0; mf < 4; ++mf){
    int n0 = nt*64 + mf*16 + g4*4;
    f32x4 res = *(const f32x4*)(x + cbase + n0);
    f32x4 ov;
    #pragma unroll
    for (int r = 0; r < 4; ++r) ov[r] = acc[mf][r] + bias + res[r];
    *(f32x4*)(out + cbase + n0) = ov;
  }
}

extern "C" void kernel_launch(void* const* d_in, const int* in_sizes, int n_in,
                              void* d_out, int out_size, void* d_ws, size_t ws_size,
                              hipStream_t stream) {
  const float* x     = (const float*)d_in[0];
  const float* gamma = (const float*)d_in[1];
  const float* beta  = (const float*)d_in[2];
  const float* wqkv  = (const float*)d_in[3];
  const float* bqkv  = (const float*)d_in[4];
  const float* wproj = (const float*)d_in[5];
  const float* bproj = (const float*)d_in[6];
  float* out = (float*)d_out;

  const size_t MiB = 1024*1024;
  char* ws = (char*)d_ws;
  float2* part   = (float2*)(ws + 0);            // 8 KB
  ushort* wq_b   = (ushort*)(ws + 16384);        // 384 KB
  ushort* wp_b   = (ushort*)(ws + 409600);       // 128 KB
  ushort* Qb     = (ushort*)(ws + 1*MiB);        // 4 MiB  [bh][n][d]
  ushort* Kb     = (ushort*)(ws + 5*MiB);        // 4 MiB  [bh][n][d]
  ushort* Vb     = (ushort*)(ws + 9*MiB);        // 4 MiB  [bh][d][n]
  ushort* Xn     = (ushort*)(ws + 13*MiB);       // 4 MiB  [b][n][c] (dead after k_qkv)
  ushort* AO     = (ushort*)(ws + 13*MiB);       // 4 MiB  [b][n][c] (reuses Xn)
  ushort* Opart  = (ushort*)(ws + 17*MiB);       // 4 or 8 MiB
  int split = (ws_size >= 27*MiB) ? 2 : 1;
  float2* ML     = (float2*)(ws + (17 + 4*(size_t)split)*MiB);  // 256/512 KB

  k_prep<<<768, 256, 0, stream>>>(wqkv, wproj, wq_b, wp_b);
  k_gn1 <<<1024, 256, 0, stream>>>(x, part);
  k_norm<<<dim3(64,4,2), 256, 0, stream>>>(x, gamma, beta, part, Xn);
  k_qkv <<<dim3(64,12,2), 256, 0, stream>>>(Xn, wq_b, bqkv, Qb, Kb, Vb);
  if (split == 2){
    k_attn<2><<<1024, 256, 0, stream>>>(Qb, Kb, Vb, Opart, ML);
    k_comb<2><<<dim3(64,8), 256, 0, stream>>>(Opart, ML, AO);
  } else {
    k_attn<1><<<512, 256, 0, stream>>>(Qb, Kb, Vb, Opart, ML);
    k_comb<1><<<dim3(64,8), 256, 0, stream>>>(Opart, ML, AO);
  }
  k_proj<<<dim3(64,4,2), 256, 0, stream>>>(AO, wp_b, bproj, x, out);
}

// Round 4
// 174.340 us; speedup vs baseline: 1.2608x; 1.2608x over previous
//
#include <hip/hip_runtime.h>
#include <stdint.h>

#define EPS 1e-5f

typedef float f32x4 __attribute__((ext_vector_type(4)));
typedef float f32x16 __attribute__((ext_vector_type(16)));
typedef __bf16 bf16x8 __attribute__((ext_vector_type(8)));
typedef uint32_t u32x4 __attribute__((ext_vector_type(4)));

__device__ __forceinline__ ushort f2bf(float f){
  union { float f; uint32_t u; } v; v.f = f;
  uint32_t r = v.u + 0x7fffu + ((v.u >> 16) & 1u);
  return (ushort)(r >> 16);
}

__device__ __forceinline__ float bf2f(ushort u){
  union { uint32_t u; float f; } v; v.u = ((uint32_t)u) << 16;
  return v.f;
}

__device__ __forceinline__ uint32_t pk2bf(float a, float b){
  __bf16 x = (__bf16)a, y = (__bf16)b;
  return (uint32_t)__builtin_bit_cast(ushort, x) |
         ((uint32_t)__builtin_bit_cast(ushort, y) << 16);
}

__device__ __forceinline__ f32x4 mfma16(bf16x8 a, bf16x8 b, f32x4 c){
  return __builtin_amdgcn_mfma_f32_16x16x32_bf16(a, b, c, 0, 0, 0);
}
__device__ __forceinline__ f32x16 mfma32(bf16x8 a, bf16x8 b, f32x16 c){
  return __builtin_amdgcn_mfma_f32_32x32x16_bf16(a, b, c, 0, 0, 0);
}

// ---------------- fused: weight cast + groupnorm stats stage 1 ----------------
// grid 1792: [0,768) weight cast, [768,1792) gn partial sums
__global__ __launch_bounds__(256) void k_pg(const float* wq, const float* wp, const float* x,
                                            ushort* wqb, ushort* wpb, float2* part){
  __shared__ float red[8];
  int bid = blockIdx.x;
  if (bid < 768){
    int i = bid * 256 + threadIdx.x;
    if (i < 3*256*256) wqb[i] = f2bf(wq[i]);
    if (i < 256*256)   wpb[i] = f2bf(wp[i]);
    return;
  }
  int gb = bid - 768;
  int bg = gb >> 6, pb = gb & 63;
  const f32x4* base = (const f32x4*)(x + (size_t)bg*131072 + (size_t)pb*2048);
  float s = 0.f, ss = 0.f;
  #pragma unroll
  for (int it = 0; it < 2; ++it){
    f32x4 v = base[threadIdx.x + it*256];
    #pragma unroll
    for (int j = 0; j < 4; ++j){ s += v[j]; ss += v[j]*v[j]; }
  }
  #pragma unroll
  for (int off = 1; off < 64; off <<= 1){
    s  += __shfl_xor(s,  off);
    ss += __shfl_xor(ss, off);
  }
  int wid = threadIdx.x >> 6;
  if ((threadIdx.x & 63) == 0){ red[wid] = s; red[4 + wid] = ss; }
  __syncthreads();
  if (threadIdx.x == 0){
    part[gb] = make_float2(red[0]+red[1]+red[2]+red[3],
                           red[4]+red[5]+red[6]+red[7]);
  }
}

// ---------------- fused GN finish + normalize + QKV GEMM ----------------
// grid (128 nt-of-32, 2 b) x 512; writes Qb/Kb [bh][n][d], Vb [bh][d][n]
__global__ __launch_bounds__(512) void k_nqkv(const float* x, const float* gamma, const float* beta,
                                              const float2* part, const ushort* wqb, const float* bqkv,
                                              ushort* Qb, ushort* Kb, ushort* Vb){
  __shared__ ushort A[32][264];    // [n][c]
  __shared__ ushort Cl[32][136];   // [n][o_local]
  __shared__ float2 st[8];
  int nt = blockIdx.x, b = blockIdx.y;
  int t = threadIdx.x, lane = t & 63, wid = t >> 6;

  // finish GN stats (8 waves x 8 groups)
  {
    float2 p = part[(b*8 + wid)*64 + lane];
    float s = p.x, ss = p.y;
    #pragma unroll
    for (int off = 1; off < 64; off <<= 1){
      s  += __shfl_xor(s,  off);
      ss += __shfl_xor(ss, off);
    }
    if (lane == 0){
      const float inv = 1.f / 131072.f;
      float mean = s * inv;
      float var  = ss * inv - mean*mean;
      st[wid] = make_float2(mean, rsqrtf(var + EPS));
    }
  }
  __syncthreads();

  // normalize x-tile [256c x 32n] -> A[n][c] bf16
  {
    int c = t >> 1, nh = t & 1;
    float2 s0 = st[c >> 5];
    float g  = gamma[c] * s0.y;
    float bt = beta[c] - s0.x * g;
    const float* xr = x + ((size_t)(b*256 + c))*4096 + nt*32 + nh*16;
    #pragma unroll
    for (int j4 = 0; j4 < 4; ++j4){
      f32x4 v = *(const f32x4*)(xr + j4*4);
      #pragma unroll
      for (int e = 0; e < 4; ++e) A[nh*16 + j4*4 + e][c] = f2bf(v[e]*g + bt);
    }
  }
  __syncthreads();

  // GEMM: C[32n x 768o] = A x W^T
  int l15 = lane & 15, g4 = lane >> 4;
  f32x4 acc[6][2];
  #pragma unroll
  for (int of = 0; of < 6; ++of)
    #pragma unroll
    for (int mf = 0; mf < 2; ++mf) acc[of][mf] = (f32x4){0.f,0.f,0.f,0.f};

  #pragma unroll
  for (int ks = 0; ks < 8; ++ks){
    bf16x8 a0 = *(const bf16x8*)&A[l15][ks*32 + g4*8];
    bf16x8 a1 = *(const bf16x8*)&A[16 + l15][ks*32 + g4*8];
    #pragma unroll
    for (int of = 0; of < 6; ++of){
      int o = of*128 + wid*16 + l15;
      bf16x8 bw = *(const bf16x8*)(wqb + (size_t)o*256 + ks*32 + g4*8);
      acc[of][0] = mfma16(a0, bw, acc[of][0]);
      acc[of][1] = mfma16(a1, bw, acc[of][1]);
    }
  }

  // epilogue: per 128-o slab, stage in LDS, coalesced writeout
  #pragma unroll
  for (int of = 0; of < 6; ++of){
    __syncthreads();
    int o = of*128 + wid*16 + l15;
    float bias = bqkv[o];
    #pragma unroll
    for (int mf = 0; mf < 2; ++mf)
      #pragma unroll
      for (int r = 0; r < 4; ++r)
        Cl[mf*16 + g4*4 + r][wid*16 + l15] = f2bf(acc[of][mf][r] + bias);
    __syncthreads();
    if (of < 4){
      // Q or K: [bh][n][d]
      ushort* basep = (of < 2) ? Qb : Kb;
      int nl = t >> 4, oc = (t & 15) * 8;
      int h = (of & 1)*2 + (oc >> 6), d0 = oc & 63;
      ushort* dst = basep + (((size_t)(b*4 + h))*4096 + nt*32 + nl)*64 + d0;
      *(uint4*)dst = *(uint4*)&Cl[nl][oc];
    } else {
      // V: [bh][d][n]
      int dl = t >> 2, nc = (t & 3) * 8;
      int h = (of - 4)*2 + (dl >> 6), d = dl & 63;
      uint32_t pk[4];
      #pragma unroll
      for (int j = 0; j < 4; ++j){
        uint32_t lo = Cl[nc + 2*j][dl], hiu = Cl[nc + 2*j + 1][dl];
        pk[j] = lo | (hiu << 16);
      }
      ushort* dst = Vb + (((size_t)(b*4 + h))*64 + d)*4096 + nt*32 + nc;
      *(uint4*)dst = make_uint4(pk[0], pk[1], pk[2], pk[3]);
    }
  }
}

// ---------------- flash attention: 32x32 MFMA, zero LDS, zero barriers ----------------
// grid 128*SPLIT x 256 (4 indep waves, each 64q x kv-range); XCD-swizzled (bh per XCD)
template<int SPLIT>
__global__ __launch_bounds__(256, 2) void k_attn(const ushort* Qb, const ushort* Kb,
                                                 const ushort* Vb, ushort* Opart, float2* ML){
  const float SCL2 = 0.125f * 1.44269504f;   // scale * log2(e)
  const int per_xcd = 16 * SPLIT;
  int xb = (blockIdx.x & 7) * per_xcd + (blockIdx.x >> 3);
  int bh = xb / per_xcd;
  int within = xb % per_xcd;
  int sp = within >> 4, q4 = within & 15;
  int t = threadIdx.x, wid = t >> 6, l = t & 63, l31 = l & 31, hi = l >> 5;
  int qt = q4*4 + wid;

  const ushort* Qg = Qb + (size_t)bh*262144;
  const ushort* Kg = Kb + (size_t)bh*262144;
  const ushort* Vg = Vb + (size_t)bh*262144;

  // Q frags [qt2][dsub]
  bf16x8 qf[2][4];
  #pragma unroll
  for (int q2 = 0; q2 < 2; ++q2)
    #pragma unroll
    for (int dsub = 0; dsub < 4; ++dsub)
      qf[q2][dsub] = *(const bf16x8*)(Qg + (size_t)(qt*64 + q2*32 + l31)*64 + dsub*16 + hi*8);

  // K A-row permutation: swap bits 2<->3 so S^T lands in P-B-frag layout
  int rowp = (l31 & 19) | ((l31 & 4) << 1) | ((l31 & 8) >> 1);
  const ushort* Kbase = Kg + (size_t)rowp*64 + hi*8;
  const ushort* Vbase = Vg + (size_t)l31*4096 + hi*8;

  f32x16 o[2][2];   // [dt][qt2]
  #pragma unroll
  for (int dt = 0; dt < 2; ++dt)
    #pragma unroll
    for (int q2 = 0; q2 < 2; ++q2)
      #pragma unroll
      for (int r = 0; r < 16; ++r) o[dt][q2][r] = 0.f;
  float m_s[2] = {-INFINITY, -INFINITY};
  float l_s[2] = {0.f, 0.f};

  const int kbBeg = sp * (64 / SPLIT), kbEnd = kbBeg + 64 / SPLIT;
  for (int kb = kbBeg; kb < kbEnd; ++kb){
    // K frags [kt][dsub]
    bf16x8 kf[2][4];
    #pragma unroll
    for (int kt = 0; kt < 2; ++kt)
      #pragma unroll
      for (int dsub = 0; dsub < 4; ++dsub)
        kf[kt][dsub] = *(const bf16x8*)(Kbase + (size_t)(kb*64 + kt*32)*64 + dsub*16);

    // QK: S^T[kv][q]
    f32x16 s[2][2];
    __builtin_amdgcn_s_setprio(1);
    #pragma unroll
    for (int kt = 0; kt < 2; ++kt)
      #pragma unroll
      for (int q2 = 0; q2 < 2; ++q2){
        f32x16 acc;
        #pragma unroll
        for (int r = 0; r < 16; ++r) acc[r] = 0.f;
        #pragma unroll
        for (int dsub = 0; dsub < 4; ++dsub)
          acc = mfma32(kf[kt][dsub], qf[q2][dsub], acc);
        s[kt][q2] = acc;
      }
    __builtin_amdgcn_s_setprio(0);

    // softmax (q lane-local; only cross-lane partner is l^32)
    float vm[2];
    #pragma unroll
    for (int q2 = 0; q2 < 2; ++q2){
      float v = s[0][q2][0];
      #pragma unroll
      for (int kt = 0; kt < 2; ++kt)
        #pragma unroll
        for (int r = 0; r < 16; ++r) v = fmaxf(v, s[kt][q2][r]);
      v = fmaxf(v, __shfl_xor(v, 32));
      vm[q2] = v * SCL2;
    }
    if (__any(fmaxf(vm[0] - m_s[0], vm[1] - m_s[1]) > 8.f)){
      #pragma unroll
      for (int q2 = 0; q2 < 2; ++q2){
        float mn = fmaxf(m_s[q2], vm[q2]);
        float a = __builtin_amdgcn_exp2f(m_s[q2] - mn);
        m_s[q2] = mn; l_s[q2] *= a;
        #pragma unroll
        for (int dt = 0; dt < 2; ++dt)
          #pragma unroll
          for (int r = 0; r < 16; ++r) o[dt][q2][r] *= a;
      }
    }
    #pragma unroll
    for (int q2 = 0; q2 < 2; ++q2){
      float r0 = 0.f, r1 = 0.f, r2 = 0.f, r3 = 0.f;
      #pragma unroll
      for (int kt = 0; kt < 2; ++kt)
        #pragma unroll
        for (int r = 0; r < 16; r += 4){
          float e0 = __builtin_amdgcn_exp2f(__builtin_fmaf(s[kt][q2][r+0], SCL2, -m_s[q2]));
          float e1 = __builtin_amdgcn_exp2f(__builtin_fmaf(s[kt][q2][r+1], SCL2, -m_s[q2]));
          float e2 = __builtin_amdgcn_exp2f(__builtin_fmaf(s[kt][q2][r+2], SCL2, -m_s[q2]));
          float e3 = __builtin_amdgcn_exp2f(__builtin_fmaf(s[kt][q2][r+3], SCL2, -m_s[q2]));
          s[kt][q2][r+0] = e0; s[kt][q2][r+1] = e1;
          s[kt][q2][r+2] = e2; s[kt][q2][r+3] = e3;
          r0 += e0; r1 += e1; r2 += e2; r3 += e3;
        }
      float rr = (r0 + r1) + (r2 + r3);
      rr += __shfl_xor(rr, 32);
      l_s[q2] += rr;
    }

    // P -> bf16 B-frags (pure in-lane thanks to the row permutation)
    bf16x8 pf[2][2][2];   // [kt][ks][qt2]
    #pragma unroll
    for (int kt = 0; kt < 2; ++kt)
      #pragma unroll
      for (int ks = 0; ks < 2; ++ks)
        #pragma unroll
        for (int q2 = 0; q2 < 2; ++q2){
          u32x4 w;
          #pragma unroll
          for (int c = 0; c < 4; ++c)
            w[c] = pk2bf(s[kt][q2][8*ks + 2*c], s[kt][q2][8*ks + 2*c + 1]);
          pf[kt][ks][q2] = __builtin_bit_cast(bf16x8, w);
        }

    // V frags [dt][c4]
    bf16x8 vf[2][4];
    #pragma unroll
    for (int dt = 0; dt < 2; ++dt)
      #pragma unroll
      for (int c4 = 0; c4 < 4; ++c4)
        vf[dt][c4] = *(const bf16x8*)(Vbase + (size_t)dt*131072 + kb*64 + c4*16);

    // PV: O^T[d][q]
    __builtin_amdgcn_s_setprio(1);
    #pragma unroll
    for (int dt = 0; dt < 2; ++dt)
      #pragma unroll
      for (int q2 = 0; q2 < 2; ++q2)
        #pragma unroll
        for (int kt = 0; kt < 2; ++kt)
          #pragma unroll
          for (int ks = 0; ks < 2; ++ks)
            o[dt][q2] = mfma32(vf[dt][kt*2 + ks], pf[kt][ks][q2], o[dt][q2]);
    __builtin_amdgcn_s_setprio(0);
  }

  // epilogue: raw partial O + (m,l)
  int pw = (bh*SPLIT + sp)*64 + qt;
  if (hi == 0){
    ML[(size_t)pw*64 + l31]      = make_float2(m_s[0], l_s[0]);
    ML[(size_t)pw*64 + 32 + l31] = make_float2(m_s[1], l_s[1]);
  }
  ushort* dst = Opart + (size_t)pw*4096;
  #pragma unroll
  for (int q2 = 0; q2 < 2; ++q2){
    int nl = q2*32 + l31;
    #pragma unroll
    for (int dt = 0; dt < 2; ++dt)
      #pragma unroll
      for (int rq = 0; rq < 4; ++rq){
        int d0 = dt*32 + rq*8 + 4*hi;
        uint2 w = make_uint2(pk2bf(o[dt][q2][rq*4+0], o[dt][q2][rq*4+1]),
                             pk2bf(o[dt][q2][rq*4+2], o[dt][q2][rq*4+3]));
        *(uint2*)(dst + (size_t)nl*64 + d0) = w;
      }
  }
}

// ---------------- combine split-KV partials -> AO[b][n][c] ----------------
// grid (64 qt, 8 bh) x 256
template<int SPLIT>
__global__ __launch_bounds__(256) void k_comb(const ushort* Opart, const float2* ML, ushort* AO){
  int qt = blockIdx.x, bh = blockIdx.y;
  int b = bh >> 2, h = bh & 3;
  int t = threadIdx.x, ql = t >> 2, d0 = (t & 3) * 16;

  float2 mls[SPLIT];
  float m = -INFINITY;
  #pragma unroll
  for (int sp = 0; sp < SPLIT; ++sp){
    mls[sp] = ML[((size_t)((bh*SPLIT + sp)*64 + qt))*64 + ql];
    m = fmaxf(m, mls[sp].x);
  }
  float den = 0.f, w[SPLIT];
  #pragma unroll
  for (int sp = 0; sp < SPLIT; ++sp){
    w[sp] = __builtin_amdgcn_exp2f(mls[sp].x - m);
    den += mls[sp].y * w[sp];
  }
  float inv = 1.f / den;

  float vals[16];
  #pragma unroll
  for (int j = 0; j < 16; ++j) vals[j] = 0.f;
  #pragma unroll
  for (int sp = 0; sp < SPLIT; ++sp){
    const ushort* src = Opart + ((size_t)((bh*SPLIT + sp)*64 + qt))*4096 + (size_t)ql*64 + d0;
    uint4 a0 = *(const uint4*)src;
    uint4 a1 = *(const uint4*)(src + 8);
    float f = w[sp] * inv;
    #pragma unroll
    for (int j = 0; j < 8; ++j) vals[j]   += bf2f(((const ushort*)&a0)[j]) * f;
    #pragma unroll
    for (int j = 0; j < 8; ++j) vals[j+8] += bf2f(((const ushort*)&a1)[j]) * f;
  }
  uint32_t pk[8];
  #pragma unroll
  for (int j = 0; j < 8; ++j) pk[j] = pk2bf(vals[2*j], vals[2*j+1]);
  ushort* dst = AO + ((size_t)b*4096 + qt*64 + ql)*256 + h*64 + d0;
  *(uint4*)dst       = make_uint4(pk[0], pk[1], pk[2], pk[3]);
  *(uint4*)(dst + 8) = make_uint4(pk[4], pk[5], pk[6], pk[7]);
}

// ---------------- proj GEMM + bias + residual ----------------
__global__ __launch_bounds__(256) void k_proj(const ushort* AO, const ushort* wpb, const float* bproj,
                                              const float* x, float* out){
  int nt = blockIdx.x, ct = blockIdx.y, b = blockIdx.z;
  int t = threadIdx.x, lane = t & 63, wid = t >> 6, l15 = lane & 15, g4 = lane >> 4;
  int o = ct*64 + wid*16 + l15;
  f32x4 acc[4];
  #pragma unroll
  for (int m = 0; m < 4; ++m) acc[m] = (f32x4){0.f,0.f,0.f,0.f};

  #pragma unroll
  for (int ks = 0; ks < 8; ++ks){
    bf16x8 bw = *(const bf16x8*)(wpb + (size_t)o*256 + ks*32 + g4*8);
    #pragma unroll
    for (int mf = 0; mf < 4; ++mf){
      int n = nt*64 + mf*16 + l15;
      bf16x8 aa = *(const bf16x8*)(AO + ((size_t)b*4096 + n)*256 + ks*32 + g4*8);
      acc[mf] = mfma16(aa, bw, acc[mf]);
    }
  }

  float bias = bproj[o];
  size_t cbase = ((size_t)b*256 + o)*4096;
  #pragma unroll
  for (int mf = 0; mf < 4; ++mf){
    int n0 = nt*64 + mf*16 + g4*4;
    f32x4 res = *(const f32x4*)(x + cbase + n0);
    f32x4 ov;
    #pragma unroll
    for (int r = 0; r < 4; ++r) ov[r] = acc[mf][r] + bias + res[r];
    *(f32x4*)(out + cbase + n0) = ov;
  }
}

extern "C" void kernel_launch(void* const* d_in, const int* in_sizes, int n_in,
                              void* d_out, int out_size, void* d_ws, size_t ws_size,
                              hipStream_t stream) {
  const float* x     = (const float*)d_in[0];
  const float* gamma = (const float*)d_in[1];
  const float* beta  = (const float*)d_in[2];
  const float* wqkv  = (const float*)d_in[3];
  const float* bqkv  = (const float*)d_in[4];
  const float* wproj = (const float*)d_in[5];
  const float* bproj = (const float*)d_in[6];
  float* out = (float*)d_out;

  const size_t MiB = 1024*1024;
  char* ws = (char*)d_ws;
  float2* part   = (float2*)(ws + 0);            // 8 KB
  ushort* wq_b   = (ushort*)(ws + 16384);        // 384 KB
  ushort* wp_b   = (ushort*)(ws + 409600);       // 128 KB
  ushort* Qb     = (ushort*)(ws + 1*MiB);        // 4 MiB  [bh][n][d]
  ushort* Kb     = (ushort*)(ws + 5*MiB);        // 4 MiB  [bh][n][d]
  ushort* Vb     = (ushort*)(ws + 9*MiB);        // 4 MiB  [bh][d][n]
  ushort* AO     = (ushort*)(ws + 13*MiB);       // 4 MiB  [b][n][c]
  ushort* Opart  = (ushort*)(ws + 17*MiB);       // 4*split MiB

  int split = (ws_size >= 35*MiB) ? 4 : (ws_size >= 26*MiB ? 2 : 1);
  float2* ML = (float2*)(ws + (17 + 4*(size_t)split)*MiB);

  k_pg  <<<1792, 256, 0, stream>>>(wqkv, wproj, x, wq_b, wp_b, part);
  k_nqkv<<<dim3(128,2), 512, 0, stream>>>(x, gamma, beta, part, wq_b, bqkv, Qb, Kb, Vb);
  if (split == 4){
    k_attn<4><<<512, 256, 0, stream>>>(Qb, Kb, Vb, Opart, ML);
    k_comb<4><<<dim3(64,8), 256, 0, stream>>>(Opart, ML, AO);
  } else if (split == 2){
    k_attn<2><<<256, 256, 0, stream>>>(Qb, Kb, Vb, Opart, ML);
    k_comb<2><<<dim3(64,8), 256, 0, stream>>>(Opart, ML, AO);
  } else {
    k_attn<1><<<128, 256, 0, stream>>>(Qb, Kb, Vb, Opart, ML);
    k_comb<1><<<dim3(64,8), 256, 0, stream>>>(Opart, ML, AO);
  }
  k_proj<<<dim3(64,4,2), 256, 0, stream>>>(AO, wp_b, bproj, x, out);
}